// Round 2
// baseline (863.366 us; speedup 1.0000x reference)
//
#include <hip/hip_runtime.h>
#include <math.h>

#define NB 4
#define SEQ 4096
#define DM 512
#define NH 8
#define HD 64
#define UU 27
#define NIDX (SEQ*UU)   // 110592
#define NC 32           // key chunks per (b,h) in attn_part
#define CS 128          // chunk size (keys)
#define PSTRIDE 66      // per-(bh,chunk,u) partial: m, l, acc[64]
#define LDP 40          // LDS row pitch in shorts (80 B -> conflict-free b128 frag reads)

typedef unsigned int u32;
typedef unsigned short u16;
typedef __attribute__((ext_vector_type(8))) short short8;
typedef __attribute__((ext_vector_type(4))) short short4v;
typedef __attribute__((ext_vector_type(4))) float f32x4;

__host__ __device__ inline u32 rotl32(u32 x, u32 r){ return (x<<r)|(x>>(32u-r)); }

// Exact JAX threefry2x32 block cipher.
__host__ __device__ inline void threefry2x32(u32 k0, u32 k1, u32 x0, u32 x1, u32* o0, u32* o1)
{
  u32 ks[3] = { k0, k1, k0 ^ k1 ^ 0x1BD11BDAu };
  x0 += ks[0]; x1 += ks[1];
  const u32 rotA[4] = {13u,15u,26u,6u};
  const u32 rotB[4] = {17u,29u,16u,24u};
  for (int i = 0; i < 5; i++) {
    const u32* rot = (i & 1) ? rotB : rotA;
    for (int j = 0; j < 4; j++) { x0 += x1; x1 = rotl32(x1, rot[j]); x1 ^= x0; }
    x0 += ks[(i+1)%3];
    x1 += ks[(i+2)%3] + (u32)(i+1);
  }
  *o0 = x0; *o1 = x1;
}

__global__ __launch_bounds__(256) void gen_idx_kernel(u32 k2a, u32 k2b, int* __restrict__ idx)
{
  int i = blockIdx.x * 256 + threadIdx.x;
  if (i >= NIDX) return;
  u32 o0, o1;
  threefry2x32(k2a, k2b, 0u, (u32)i, &o0, &o1);
  idx[i] = (int)((o0 ^ o1) & (SEQ - 1));
}

__device__ inline u16 f2bf_rne(float f) {
  u32 u = __float_as_uint(f);
  return (u16)((u + 0x7fffu + ((u >> 16) & 1u)) >> 16);
}
// split: hi = truncation, lo = bf16(f - hi). |err| ~ 2^-17 relative.
__device__ inline void f2bf_split(float f, u16& hi, u16& lo) {
  u32 u = __float_as_uint(f);
  u16 h = (u16)(u >> 16);
  float hf = __uint_as_float(((u32)h) << 16);
  hi = h;
  lo = f2bf_rne(f - hf);
}

// fp32 (16384x512) -> planar bf16 hi/lo. Memory-bound, 8 elems/thread.
__global__ __launch_bounds__(256) void conv_split(const float* __restrict__ X,
                                                  u16* __restrict__ hi, u16* __restrict__ lo)
{
  long g = (long)blockIdx.x * 256 + threadIdx.x;
  float4 x0 = ((const float4*)X)[g * 2];
  float4 x1 = ((const float4*)X)[g * 2 + 1];
  union { short8 v; u16 s[8]; } h, l;
  float xv[8] = { x0.x, x0.y, x0.z, x0.w, x1.x, x1.y, x1.z, x1.w };
  #pragma unroll
  for (int e = 0; e < 8; e++) f2bf_split(xv[e], h.s[e], l.s[e]);
  ((short8*)hi)[g] = h.v;
  ((short8*)lo)[g]  = l.v;
}

// All 8 weight matrices: W (512x512, k-major) -> W^T hi/lo planes (n-major).
struct WPtrs { const float* w[8]; };
__global__ __launch_bounds__(256) void convw_kernel(WPtrs wp, u16* __restrict__ outp)
{
  const int n  = blockIdx.x;     // output row = W column
  const int wi = blockIdx.y;
  const float* W = wp.w[wi];
  u16* hi = outp + (long)wi * 524288 + n * DM;
  u16* lo = hi + 262144;
  for (int k = threadIdx.x; k < DM; k += 256) {
    u16 h, l;
    f2bf_split(W[(long)k * DM + n], h, l);
    hi[k] = h; lo[k] = l;
  }
}

// MFMA GEMM on pre-converted bf16 planes: C(16384,512) = A @ W + bias [+resid].
// A: hi/lo planar bf16 row-major; W: hi/lo planar bf16 TRANSPOSED (n-major).
// No conversion in the hot loop; staging is 8 dwordx4 + 8 ds_write_b128/thread/K-step.
// Numerics: identical f2bf_split values and identical MFMA order as the
// previous in-kernel-convert version -> bitwise-identical output.
template<int SPLIT>
__global__ __launch_bounds__(256) void gemm_bf(
    const u16* __restrict__ Ah, const u16* __restrict__ Al,
    const u16* __restrict__ Wh, const u16* __restrict__ Wl,
    const float* __restrict__ bias, float* __restrict__ C,
    const float* __restrict__ resid, int rowJump)
{
  __shared__ short As_hi[128 * LDP];
  __shared__ short Ws_hi[128 * LDP];
  __shared__ short As_lo[SPLIT ? 128 * LDP : 8];
  __shared__ short Ws_lo[SPLIT ? 128 * LDP : 8];

  const int t  = threadIdx.x;
  const int rb = blockIdx.x * 128;
  const int cb = blockIdx.y * 128;

  // staging map: thread covers rows r0 and r0+64, 8-short segment sg
  const int r0 = t >> 2, sg = (t & 3) * 8;
  const u16* pAh0 = Ah + (long)(rb + r0) * DM + sg;
  const u16* pAh1 = pAh0 + (long)64 * DM;
  const u16* pWh0 = Wh + (long)(cb + r0) * DM + sg;
  const u16* pWh1 = pWh0 + (long)64 * DM;
  const u16* pAl0 = SPLIT ? (Al + (long)(rb + r0) * DM + sg) : pAh0;
  const u16* pAl1 = pAl0 + (long)64 * DM;
  const u16* pWl0 = SPLIT ? (Wl + (long)(cb + r0) * DM + sg) : pWh0;
  const u16* pWl1 = pWl0 + (long)64 * DM;

  short* dA0 = &As_hi[r0 * LDP + sg];
  short* dA1 = &As_hi[(r0 + 64) * LDP + sg];
  short* dW0 = &Ws_hi[r0 * LDP + sg];
  short* dW1 = &Ws_hi[(r0 + 64) * LDP + sg];
  short* dAl0 = &As_lo[SPLIT ? r0 * LDP + sg : 0];
  short* dAl1 = &As_lo[SPLIT ? (r0 + 64) * LDP + sg : 0];
  short* dWl0 = &Ws_lo[SPLIT ? r0 * LDP + sg : 0];
  short* dWl1 = &Ws_lo[SPLIT ? (r0 + 64) * LDP + sg : 0];

  // fragment indices
  const int lane = t & 63, wv = t >> 6;
  const int wm = (wv & 1) * 64, wn = (wv >> 1) * 64;
  const int fr = lane & 15, fq = lane >> 4;

  f32x4 acc[4][4];
  #pragma unroll
  for (int i = 0; i < 4; i++)
    #pragma unroll
    for (int j = 0; j < 4; j++) acc[i][j] = (f32x4)(0.f);

  for (int k0 = 0; k0 < DM; k0 += 32) {
    // ---- global loads (before barrier) ----
    short8 va0 = *(const short8*)(pAh0 + k0);
    short8 va1 = *(const short8*)(pAh1 + k0);
    short8 vw0 = *(const short8*)(pWh0 + k0);
    short8 vw1 = *(const short8*)(pWh1 + k0);
    short8 la0, la1, lw0, lw1;
    if (SPLIT) {
      la0 = *(const short8*)(pAl0 + k0);
      la1 = *(const short8*)(pAl1 + k0);
      lw0 = *(const short8*)(pWl0 + k0);
      lw1 = *(const short8*)(pWl1 + k0);
    }

    __syncthreads();   // previous iteration's frag reads done

    *(short8*)dA0 = va0; *(short8*)dA1 = va1;
    *(short8*)dW0 = vw0; *(short8*)dW1 = vw1;
    if (SPLIT) {
      *(short8*)dAl0 = la0; *(short8*)dAl1 = la1;
      *(short8*)dWl0 = lw0; *(short8*)dWl1 = lw1;
    }
    __syncthreads();

    // ---- fragments + MFMA ----
    short8 a_hi[4], b_hi[4];
    #pragma unroll
    for (int i = 0; i < 4; i++)
      a_hi[i] = *(const short8*)&As_hi[(wm + i * 16 + fr) * LDP + fq * 8];
    #pragma unroll
    for (int j = 0; j < 4; j++)
      b_hi[j] = *(const short8*)&Ws_hi[(wn + j * 16 + fr) * LDP + fq * 8];
    #pragma unroll
    for (int i = 0; i < 4; i++)
      #pragma unroll
      for (int j = 0; j < 4; j++)
        acc[i][j] = __builtin_amdgcn_mfma_f32_16x16x32_bf16(a_hi[i], b_hi[j], acc[i][j], 0, 0, 0);
    if (SPLIT) {
      short8 a_lo[4], b_lo[4];
      #pragma unroll
      for (int i = 0; i < 4; i++)
        a_lo[i] = *(const short8*)&As_lo[(wm + i * 16 + fr) * LDP + fq * 8];
      #pragma unroll
      for (int j = 0; j < 4; j++)
        b_lo[j] = *(const short8*)&Ws_lo[(wn + j * 16 + fr) * LDP + fq * 8];
      #pragma unroll
      for (int i = 0; i < 4; i++)
        #pragma unroll
        for (int j = 0; j < 4; j++) {
          acc[i][j] = __builtin_amdgcn_mfma_f32_16x16x32_bf16(a_hi[i], b_lo[j], acc[i][j], 0, 0, 0);
          acc[i][j] = __builtin_amdgcn_mfma_f32_16x16x32_bf16(a_lo[i], b_hi[j], acc[i][j], 0, 0, 0);
        }
    }
  }

  // ---- epilogue: D layout col=lane&15, row=fq*4+reg ----
  #pragma unroll
  for (int j = 0; j < 4; j++) {
    int col = cb + wn + j * 16 + fr;
    float bv = bias[col];
    #pragma unroll
    for (int i = 0; i < 4; i++) {
      int row0 = rb + wm + i * 16 + fq * 4;
      #pragma unroll
      for (int r = 0; r < 4; r++) {
        int row = row0 + r;
        long off = (long)row * DM + (long)(row >> 12) * rowJump + col;
        float v = acc[i][j][r] + bv;
        if (resid) v += resid[off];
        C[off] = v;
      }
    }
  }
}

// M[b,h,l] for ALL 8 heads by one wave per (b,l): lane = h*8+j, 8 dims/lane.
// L2-locality: 27 samples visited in 8 passes over 512-row K chunks.
__global__ __launch_bounds__(256) void mscore_kernel(const float* __restrict__ Q, const float* __restrict__ K,
                                                     const int* __restrict__ idx, float* __restrict__ M)
{
  const int wl = threadIdx.x >> 6, lane = threadIdx.x & 63;
  const int bl = blockIdx.x * 4 + wl;       // b*4096 + l
  const int b = bl >> 12, l = bl & (SEQ - 1);

  const float4* qp = (const float4*)(Q + (long)bl * DM + lane * 8);
  float4 q0 = qp[0], q1 = qp[1];

  const int* ip = idx + l * UU;
  int idxv = ip[lane < UU ? lane : 0];
  int chv = idxv >> 9;                      // chunk id (512 rows/chunk)

  const float* kb = K + ((long)b << 12) * DM + lane * 8;
  float mx = -INFINITY, sm = 0.f;
  #pragma unroll 1
  for (int c = 0; c < 8; c++) {
    unsigned long long msk = __ballot(chv == c) & ((1ull << UU) - 1ull);
    while (msk) {
      int s = __builtin_ctzll(msk);
      msk &= msk - 1;
      int kl = __shfl(idxv, s, 64);
      const float4* kp = (const float4*)(kb + (long)kl * DM);
      float4 k0 = kp[0], k1 = kp[1];
      float dot;
      dot = q0.x * k0.x;
      dot = fmaf(q0.y, k0.y, dot); dot = fmaf(q0.z, k0.z, dot); dot = fmaf(q0.w, k0.w, dot);
      dot = fmaf(q1.x, k1.x, dot); dot = fmaf(q1.y, k1.y, dot);
      dot = fmaf(q1.z, k1.z, dot); dot = fmaf(q1.w, k1.w, dot);
      dot += __shfl_xor(dot, 1, 64);
      dot += __shfl_xor(dot, 2, 64);
      dot += __shfl_xor(dot, 4, 64);
      mx = fmaxf(mx, dot);
      sm += dot;
    }
  }
  if ((lane & 7) == 0) {
    int h = lane >> 3;
    M[(((long)b * NH + h) << 12) + l] = mx - sm * (1.0f / (float)SEQ);
  }
}

// Stable top-27 of 4096 per (b,h). Ties: lower index first (lax.top_k).
__global__ __launch_bounds__(256) void topk_kernel(const float* __restrict__ M, int* __restrict__ topidx)
{
  __shared__ float vals[SEQ];
  __shared__ float rv[256];
  __shared__ int   ri[256];
  const float* m = M + (long)blockIdx.x * SEQ;
  for (int i = threadIdx.x; i < SEQ; i += 256) vals[i] = m[i];
  __syncthreads();
  for (int it = 0; it < UU; it++) {
    float bv = -INFINITY; int bi = 0x7fffffff;
    for (int i = threadIdx.x; i < SEQ; i += 256) {
      float v = vals[i];
      if (v > bv) { bv = v; bi = i; }
    }
    rv[threadIdx.x] = bv; ri[threadIdx.x] = bi;
    __syncthreads();
    for (int s = 128; s > 0; s >>= 1) {
      if (threadIdx.x < s) {
        float ov = rv[threadIdx.x + s]; int oi = ri[threadIdx.x + s];
        if (ov > rv[threadIdx.x] || (ov == rv[threadIdx.x] && oi < ri[threadIdx.x])) {
          rv[threadIdx.x] = ov; ri[threadIdx.x] = oi;
        }
      }
      __syncthreads();
    }
    if (threadIdx.x == 0) { topidx[blockIdx.x * UU + it] = ri[0]; vals[ri[0]] = -INFINITY; }
    __syncthreads();
  }
}

__global__ __launch_bounds__(512) void vmean_partial(const float* __restrict__ V, float* __restrict__ vsum)
{
  int b = blockIdx.x >> 5, chunk = blockIdx.x & 31;
  int c = threadIdx.x;
  const float* p = V + ((long)b * SEQ + chunk * 128) * DM + c;
  float s = 0.f;
  for (int l = 0; l < 128; l++) s += p[(long)l * DM];
  atomicAdd(&vsum[b * DM + c], s);
}

// Flash-style chunked attention for the 27 selected queries.
__global__ __launch_bounds__(256) void attn_part(const float* __restrict__ Q, const float* __restrict__ K,
                                                 const float* __restrict__ V, const int* __restrict__ topidx,
                                                 float* __restrict__ partial)
{
  __shared__ float Qs[UU][HD];
  __shared__ float S[UU][CS];
  __shared__ float Vt[CS][HD];
  __shared__ float m_s[UU], l_s[UU];

  const int t = threadIdx.x;
  const int bh = blockIdx.x;
  const int chunk = blockIdx.y;
  const int b = bh >> 3, h = bh & 7;
  const long kbase = ((long)(b << 12) + chunk * CS) * DM + h * HD;
  const int* tp = topidx + bh * UU;

  for (int i = t; i < UU * HD; i += 256) {
    int u = i >> 6, d = i & 63;
    Qs[u][d] = Q[((long)(b << 12) + tp[u]) * DM + h * HD + d];
  }
  for (int i = t; i < CS * (HD / 4); i += 256) {
    int row = i >> 4, c4 = (i & 15) << 2;
    *(float4*)&Vt[row][c4] = *(const float4*)(V + kbase + (long)row * DM + c4);
  }
  __syncthreads();

  {
    const int l = t >> 1, half = t & 1, d0 = half * 32;
    const float* kp = K + kbase + (long)l * DM + d0;
    float4 kr[8];
    #pragma unroll
    for (int j = 0; j < 8; j++) kr[j] = *(const float4*)(kp + j * 4);
    #pragma unroll 1
    for (int u = 0; u < UU; u++) {
      const float4* qf = (const float4*)&Qs[u][d0];
      float dot = 0.f;
      #pragma unroll
      for (int j = 0; j < 8; j++) {
        float4 q = qf[j];
        dot = fmaf(q.x, kr[j].x, dot); dot = fmaf(q.y, kr[j].y, dot);
        dot = fmaf(q.z, kr[j].z, dot); dot = fmaf(q.w, kr[j].w, dot);
      }
      float tot = dot + __shfl_xor(dot, 1, 64);
      if (half == 0) S[u][l] = tot * 0.125f;
    }
  }
  __syncthreads();

  {
    const int u = t >> 3, il = t & 7;
    if (u < UU) {
      float mx = -INFINITY;
      for (int l = il; l < CS; l += 8) mx = fmaxf(mx, S[u][l]);
      #pragma unroll
      for (int m = 1; m < 8; m <<= 1) mx = fmaxf(mx, __shfl_xor(mx, m, 64));
      float ps = 0.f;
      for (int l = il; l < CS; l += 8) {
        float e = expf(S[u][l] - mx);
        S[u][l] = e;
        ps += e;
      }
      #pragma unroll
      for (int m = 1; m < 8; m <<= 1) ps += __shfl_xor(ps, m, 64);
      if (il == 0) { m_s[u] = mx; l_s[u] = ps; }
    }
  }
  __syncthreads();

  {
    const int d = t & 63, g = t >> 6;
    for (int u = g; u < UU; u += 4) {
      float acc = 0.f;
      #pragma unroll 4
      for (int l = 0; l < CS; l += 4) {
        float4 p4 = *(const float4*)&S[u][l];
        acc = fmaf(p4.x, Vt[l][d],     acc);
        acc = fmaf(p4.y, Vt[l + 1][d], acc);
        acc = fmaf(p4.z, Vt[l + 2][d], acc);
        acc = fmaf(p4.w, Vt[l + 3][d], acc);
      }
      float* pp = partial + (((long)bh * NC + chunk) * UU + u) * PSTRIDE;
      pp[2 + d] = acc;
      if (d == 0) { pp[0] = m_s[u]; pp[1] = l_s[u]; }
    }
  }
}

// Merge partials; write result directly into bf16 hi/lo planes (split).
__global__ __launch_bounds__(64) void attn_merge_bf(const float* __restrict__ partial, const int* __restrict__ topidx,
                                                    u16* __restrict__ hi, u16* __restrict__ lo)
{
  int g = blockIdx.x;
  int bh = g / UU, u = g % UU;
  int b = bh >> 3, h = bh & 7;
  int d = threadIdx.x;
  float M = -INFINITY, S = 0.f, acc = 0.f;
  for (int c = 0; c < NC; c++) {
    const float* pp = partial + (((long)bh * NC + c) * UU + u) * PSTRIDE;
    float mc = pp[0], sc = pp[1], a = pp[2 + d];
    if (mc > M) {
      float r = expf(M - mc);
      acc *= r; S *= r; M = mc;
    }
    float w = expf(mc - M);
    acc = fmaf(a, w, acc);
    S = fmaf(sc, w, S);
  }
  int ql = topidx[g];
  long o = ((long)(b << 12) + ql) * DM + h * HD + d;
  u16 hv, lv;
  f2bf_split(acc / S, hv, lv);
  hi[o] = hv; lo[o] = lv;
}

// Broadcast V-mean into the ctx bf16 hi/lo planes (split).
__global__ __launch_bounds__(256) void ctx_fill_bf(const float* __restrict__ vsum,
                                                   u16* __restrict__ hi, u16* __restrict__ lo)
{
  long g = (long)blockIdx.x * 256 + threadIdx.x;   // 4 elems per thread
  int b = (int)(g >> 19);
  int c4 = (int)(g & 127);
  float4 v = ((const float4*)vsum)[b * 128 + c4];
  const float s = 1.0f / (float)SEQ;
  float xv[4] = { v.x * s, v.y * s, v.z * s, v.w * s };
  union { short4v v; u16 s[4]; } h, l;
  #pragma unroll
  for (int e = 0; e < 4; e++) f2bf_split(xv[e], h.s[e], l.s[e]);
  ((short4v*)hi)[g] = h.v;
  ((short4v*)lo)[g]  = l.v;
}

__global__ __launch_bounds__(256) void add_upper(const float* __restrict__ xs, const float* __restrict__ xp2,
                                                 float* __restrict__ out)
{
  long g = (long)blockIdx.x * 256 + threadIdx.x;
  int b = (int)(g >> 19);
  long rem = g & 524287;
  float4 p = ((const float4*)xp2)[g];
  long o = ((long)b * 8192 + SEQ) * 128 + rem;
  float4 x = ((const float4*)xs)[o];
  x.x += p.x; x.y += p.y; x.z += p.z; x.w += p.w;
  ((float4*)out)[o] = x;
}

extern "C" void kernel_launch(void* const* d_in, const int* in_sizes, int n_in,
                              void* d_out, int out_size, void* d_ws, size_t ws_size,
                              hipStream_t stream)
{
  const float* xs  = (const float*)d_in[0];
  const float* xd  = (const float*)d_in[1];
  const float* xp  = (const float*)d_in[2];
  const float* w0q = (const float*)d_in[3];
  const float* w0k = (const float*)d_in[4];
  const float* w0v = (const float*)d_in[5];
  const float* w0o = (const float*)d_in[6];
  const float* b0q = (const float*)d_in[7];
  const float* b0k = (const float*)d_in[8];
  const float* b0v = (const float*)d_in[9];
  const float* b0o = (const float*)d_in[10];
  const float* w1q = (const float*)d_in[11];
  const float* w1k = (const float*)d_in[12];
  const float* w1v = (const float*)d_in[13];
  const float* w1o = (const float*)d_in[14];
  const float* b1q = (const float*)d_in[15];
  const float* b1k = (const float*)d_in[16];
  const float* b1v = (const float*)d_in[17];
  const float* b1o = (const float*)d_in[18];
  float* out = (float*)d_out;

  const long BIG = (long)NB * SEQ * DM;   // 8 Mi floats = 32 MB
  float* A  = (float*)d_ws;
  float* Bb = A  + BIG;
  float* Cc = Bb + BIG;
  float* Dd = Cc + BIG;
  float* ex = Dd + BIG;
  float* Pq  = ex + BIG;     // plane pair 1: hi | lo (bf16)
  float* Pkv = Pq + BIG;     // plane pair 2

  int*   idxbuf = (int*)ex;
  float* Mbuf   = ex + NIDX;
  int*   topidx = (int*)(Mbuf + (long)NB * NH * SEQ);
  float* vsum   = (float*)(topidx + NB * NH * UU);
  u16*   wpl    = (u16*)(ex + (1 << 20));   // +4 MB: 8 x (hi|lo) W^T planes, 8 MB

  u16* Pq_hi  = (u16*)Pq;   u16* Pq_lo  = Pq_hi  + BIG;
  u16* Pkv_hi = (u16*)Pkv;  u16* Pkv_lo = Pkv_hi + BIG;
  auto whi = [&](int i){ return wpl + (long)i * 524288; };
  auto wlo = [&](int i){ return wpl + (long)i * 524288 + 262144; };

  dim3 gg(128, 4);
  dim3 ag(NB * NH, NC);
  u32 k2a, k2b;

  // ---------- one-time: W^T hi/lo planes for all 8 weights ----------
  WPtrs wp;
  wp.w[0] = w0q; wp.w[1] = w0k; wp.w[2] = w0v; wp.w[3] = w0o;
  wp.w[4] = w1q; wp.w[5] = w1k; wp.w[6] = w1v; wp.w[7] = w1o;
  convw_kernel<<<dim3(512, 8), 256, 0, stream>>>(wp, wpl);

  // ---------- layer 0: xp2 = attn_layer(q=xp; kv=xd), key 42 ----------
  threefry2x32(0u, 42u, 0u, 1u, &k2a, &k2b);
  gen_idx_kernel<<<(NIDX + 255) / 256, 256, 0, stream>>>(k2a, k2b, idxbuf);
  conv_split<<<4096, 256, 0, stream>>>(xp, Pq_hi, Pq_lo);
  conv_split<<<4096, 256, 0, stream>>>(xd, Pkv_hi, Pkv_lo);
  gemm_bf<1><<<gg, 256, 0, stream>>>(Pq_hi,  Pq_lo,  whi(0), wlo(0), b0q, A,  nullptr, 0);
  gemm_bf<1><<<gg, 256, 0, stream>>>(Pkv_hi, Pkv_lo, whi(1), wlo(1), b0k, Bb, nullptr, 0);
  gemm_bf<1><<<gg, 256, 0, stream>>>(Pkv_hi, Pkv_lo, whi(2), wlo(2), b0v, Cc, nullptr, 0);
  mscore_kernel<<<NB * SEQ / 4, 256, 0, stream>>>(A, Bb, idxbuf, Mbuf);
  topk_kernel<<<NB * NH, 256, 0, stream>>>(Mbuf, topidx);
  hipMemsetAsync(vsum, 0, NB * DM * sizeof(float), stream);
  vmean_partial<<<NB * 32, 512, 0, stream>>>(Cc, vsum);
  attn_part<<<ag, 256, 0, stream>>>(A, Bb, Cc, topidx, Dd);
  ctx_fill_bf<<<8192, 256, 0, stream>>>(vsum, Pq_hi, Pq_lo);          // ctx planes (Pq free: consumed by Q-gemm)
  attn_merge_bf<<<NB * NH * UU, 64, 0, stream>>>(Dd, topidx, Pq_hi, Pq_lo);
  gemm_bf<1><<<gg, 256, 0, stream>>>(Pq_hi, Pq_lo, whi(3), wlo(3), b0o, Bb, nullptr, 0);  // xp2 fp32
  add_upper<<<8192, 256, 0, stream>>>(xs, Bb, out);

  // ---------- layer 1: xd2 = attn_layer(q=xd; kv=xp2), key 43 ----------
  threefry2x32(0u, 43u, 0u, 1u, &k2a, &k2b);
  gen_idx_kernel<<<(NIDX + 255) / 256, 256, 0, stream>>>(k2a, k2b, idxbuf);
  gemm_bf<1><<<gg, 256, 0, stream>>>(Pkv_hi, Pkv_lo, whi(4), wlo(4), b1q, A, nullptr, 0); // xd planes reused
  conv_split<<<4096, 256, 0, stream>>>(Bb, Pq_hi, Pq_lo);                                 // xp2 planes
  gemm_bf<1><<<gg, 256, 0, stream>>>(Pq_hi, Pq_lo, whi(5), wlo(5), b1k, Cc, nullptr, 0);
  gemm_bf<1><<<gg, 256, 0, stream>>>(Pq_hi, Pq_lo, whi(6), wlo(6), b1v, Dd, nullptr, 0);
  mscore_kernel<<<NB * SEQ / 4, 256, 0, stream>>>(A, Cc, idxbuf, Mbuf);
  topk_kernel<<<NB * NH, 256, 0, stream>>>(Mbuf, topidx);
  hipMemsetAsync(vsum, 0, NB * DM * sizeof(float), stream);
  vmean_partial<<<NB * 32, 512, 0, stream>>>(Dd, vsum);
  attn_part<<<ag, 256, 0, stream>>>(A, Cc, Dd, topidx, Bb);
  ctx_fill_bf<<<8192, 256, 0, stream>>>(vsum, Pkv_hi, Pkv_lo);        // ctx planes (Pkv free after Q-gemm)
  attn_merge_bf<<<NB * NH * UU, 64, 0, stream>>>(Bb, topidx, Pkv_hi, Pkv_lo);
  gemm_bf<1><<<gg, 256, 0, stream>>>(Pkv_hi, Pkv_lo, whi(7), wlo(7), b1o, out, xs, SEQ * DM);
}

// Round 3
// 833.439 us; speedup vs baseline: 1.0359x; 1.0359x over previous
//
#include <hip/hip_runtime.h>
#include <math.h>

#define NB 4
#define SEQ 4096
#define DM 512
#define NH 8
#define HD 64
#define UU 27
#define NIDX (SEQ*UU)   // 110592
#define NC 32           // key chunks per (b,h) in attn_part
#define CS 128          // chunk size (keys)
#define PSTRIDE 66      // per-(bh,chunk,u) partial: m, l, acc[64]

typedef unsigned int u32;
typedef unsigned short u16;
typedef __attribute__((ext_vector_type(8))) short short8;
typedef __attribute__((ext_vector_type(4))) short short4v;
typedef __attribute__((ext_vector_type(4))) float f32x4;

__host__ __device__ inline u32 rotl32(u32 x, u32 r){ return (x<<r)|(x>>(32u-r)); }

// Exact JAX threefry2x32 block cipher.
__host__ __device__ inline void threefry2x32(u32 k0, u32 k1, u32 x0, u32 x1, u32* o0, u32* o1)
{
  u32 ks[3] = { k0, k1, k0 ^ k1 ^ 0x1BD11BDAu };
  x0 += ks[0]; x1 += ks[1];
  const u32 rotA[4] = {13u,15u,26u,6u};
  const u32 rotB[4] = {17u,29u,16u,24u};
  for (int i = 0; i < 5; i++) {
    const u32* rot = (i & 1) ? rotB : rotA;
    for (int j = 0; j < 4; j++) { x0 += x1; x1 = rotl32(x1, rot[j]); x1 ^= x0; }
    x0 += ks[(i+1)%3];
    x1 += ks[(i+2)%3] + (u32)(i+1);
  }
  *o0 = x0; *o1 = x1;
}

__global__ __launch_bounds__(256) void gen_idx_kernel(u32 k2a, u32 k2b, int* __restrict__ idx)
{
  int i = blockIdx.x * 256 + threadIdx.x;
  if (i >= NIDX) return;
  u32 o0, o1;
  threefry2x32(k2a, k2b, 0u, (u32)i, &o0, &o1);
  idx[i] = (int)((o0 ^ o1) & (SEQ - 1));
}

__device__ inline u16 f2bf_rne(float f) {
  u32 u = __float_as_uint(f);
  return (u16)((u + 0x7fffu + ((u >> 16) & 1u)) >> 16);
}
// split: hi = truncation, lo = bf16(f - hi). |err| ~ 2^-17 relative.
__device__ inline void f2bf_split(float f, u16& hi, u16& lo) {
  u32 u = __float_as_uint(f);
  u16 h = (u16)(u >> 16);
  float hf = __uint_as_float(((u32)h) << 16);
  hi = h;
  lo = f2bf_rne(f - hf);
}

// fp32 (16384x512) -> planar bf16 hi/lo. Memory-bound, 8 elems/thread.
__global__ __launch_bounds__(256) void conv_split(const float* __restrict__ X,
                                                  u16* __restrict__ hi, u16* __restrict__ lo)
{
  long g = (long)blockIdx.x * 256 + threadIdx.x;
  float4 x0 = ((const float4*)X)[g * 2];
  float4 x1 = ((const float4*)X)[g * 2 + 1];
  union { short8 v; u16 s[8]; } h, l;
  float xv[8] = { x0.x, x0.y, x0.z, x0.w, x1.x, x1.y, x1.z, x1.w };
  #pragma unroll
  for (int e = 0; e < 8; e++) f2bf_split(xv[e], h.s[e], l.s[e]);
  ((short8*)hi)[g] = h.v;
  ((short8*)lo)[g]  = l.v;
}

// All 8 weight matrices: W (512x512, k-major) -> W^T planes (n-major).
// Layout: 8 hi planes (each 512x512 u16) then 8 lo planes -> hi planes of
// consecutive slots are contiguous (enables fused K|V weight, 1024 rows).
struct WPtrs { const float* w[8]; };
__global__ __launch_bounds__(256) void convw_kernel(WPtrs wp, u16* __restrict__ outp)
{
  const int n  = blockIdx.x;     // output row = W column
  const int wi = blockIdx.y;
  const float* W = wp.w[wi];
  u16* hi = outp + (long)wi * 262144 + n * DM;
  u16* lo = hi + 8L * 262144;
  for (int k = threadIdx.x; k < DM; k += 256) {
    u16 h, l;
    f2bf_split(W[(long)k * DM + n], h, l);
    hi[k] = h; lo[k] = l;
  }
}

// global -> LDS direct DMA, 16B per lane. LDS dest = wave-uniform base + lane*16.
__device__ inline void gld16(const u16* g, short* l) {
  __builtin_amdgcn_global_load_lds((const u32*)g, (u32*)l, 16, 0, 0);
}

// MFMA GEMM on pre-converted bf16 planes, m97-style staging:
//   global_load_lds width-16 (linear LDS dest, conflict-free DMA writes)
//   + XOR-swizzled tile layout achieved by PRE-SWIZZLING the per-lane global
//     source (rule 21), so swizzled ds_read_b128 frag reads are conflict-free
//   + double-buffered LDS, ONE barrier per K-step, stage issued before compute.
// Tile: BM=BN=128, BK=32, 256 thr = 4 waves, wave = 64x64 via 4x4 16x16x32 frags.
// Split numerics: hi*hi + hi*lo + lo*hi (same order as before -> bitwise identical).
// Dual output: col<512 -> C0/bias0, else C1/bias1 (K|V fusion; pass same ptr twice
// for a plain 512-col GEMM).
//
// LDS tile layout (per 128x32-short tile, 8KB): 64 super-rows of 128B.
//   logical (r, c8) [c8 = 16B block, 0..3] -> slot = (r&1)*4 + c8,
//   phys slot = slot ^ ((r>>1)&7), short idx = (r>>1)*64 + phys*8.
//   Frag-read lanes map 8-per-4-bank-group -> conflict-free.
__global__ __launch_bounds__(256) void gemm_bf(
    const u16* __restrict__ Ah, const u16* __restrict__ Al,
    const u16* __restrict__ Wh, const u16* __restrict__ Wl,
    const float* __restrict__ bias0, const float* __restrict__ bias1,
    float* __restrict__ C0, float* __restrict__ C1,
    const float* __restrict__ resid, int rowJump)
{
  __shared__ short LB[2][4][4096];   // [dbuf][Ah,Wh,Al,Wl]

  const int t  = threadIdx.x;
  const int rb = blockIdx.x * 128;
  const int cb = blockIdx.y * 128;

  // ---- staging source map (inverse of the LDS swizzle) ----
  // thread t, issue i covers linear tile bytes [ (i*256+t)*16, +16 ):
  //   super-row = i*32 + (t>>3), phys slot = t&7
  //   -> logical slot = (t&7) ^ ((t>>3)&7), row = i*64 + (t>>3)*2 + (slot>>2),
  //      c8 = slot&3.
  const int slot = (t & 7) ^ ((t >> 3) & 7);
  const int c8   = slot & 3;
  const int rloc = ((t >> 3) << 1) + (slot >> 2);
  const u16* sAh = Ah + (long)(rb + rloc) * DM + c8 * 8;
  const u16* sWh = Wh + (long)(cb + rloc) * DM + c8 * 8;
  const u16* sAl = Al + (long)(rb + rloc) * DM + c8 * 8;
  const u16* sWl = Wl + (long)(cb + rloc) * DM + c8 * 8;
  const int w512 = (t >> 6) * 512;   // wave-uniform LDS chunk (shorts)

  // ---- fragment read offsets ----
  const int lane = t & 63, wv = t >> 6;
  const int wm = (wv & 1) * 64, wn = (wv >> 1) * 64;
  const int fr = lane & 15, fq = lane >> 4;
  // logical row wm+i*16+fr, col block fq -> swizzled short offset (i-indep part):
  const int fsw = (fr >> 1) * 64 + ((((fr & 1) * 4 + fq) ^ (fr >> 1)) * 8);
  const int a_off = wm * 32 + fsw;
  const int b_off = wn * 32 + fsw;

  f32x4 acc[4][4];
  #pragma unroll
  for (int i = 0; i < 4; i++)
    #pragma unroll
    for (int j = 0; j < 4; j++) acc[i][j] = (f32x4)(0.f);

#define STAGE(buf, k0s) do { \
    gld16(sAh + (k0s),               &LB[buf][0][w512]); \
    gld16(sAh + (k0s) + 64 * DM,     &LB[buf][0][w512 + 2048]); \
    gld16(sWh + (k0s),               &LB[buf][1][w512]); \
    gld16(sWh + (k0s) + 64 * DM,     &LB[buf][1][w512 + 2048]); \
    gld16(sAl + (k0s),               &LB[buf][2][w512]); \
    gld16(sAl + (k0s) + 64 * DM,     &LB[buf][2][w512 + 2048]); \
    gld16(sWl + (k0s),               &LB[buf][3][w512]); \
    gld16(sWl + (k0s) + 64 * DM,     &LB[buf][3][w512 + 2048]); \
  } while (0)

  STAGE(0, 0);
  #pragma unroll 2
  for (int ks = 0; ks < 16; ks++) {
    const int cur = ks & 1;
    asm volatile("s_waitcnt vmcnt(0)" ::: "memory");   // buf[cur] landed
    __syncthreads();                                    // all waves past reads of buf[cur^1]
    if (ks < 15) STAGE(cur ^ 1, (ks + 1) * 32);        // loads fly under compute

    short8 a_hi[4], b_hi[4], a_lo[4], b_lo[4];
    #pragma unroll
    for (int i = 0; i < 4; i++) a_hi[i] = *(const short8*)&LB[cur][0][a_off + i * 512];
    #pragma unroll
    for (int j = 0; j < 4; j++) b_hi[j] = *(const short8*)&LB[cur][1][b_off + j * 512];
    #pragma unroll
    for (int i = 0; i < 4; i++) a_lo[i] = *(const short8*)&LB[cur][2][a_off + i * 512];
    #pragma unroll
    for (int j = 0; j < 4; j++) b_lo[j] = *(const short8*)&LB[cur][3][b_off + j * 512];

    #pragma unroll
    for (int i = 0; i < 4; i++)
      #pragma unroll
      for (int j = 0; j < 4; j++)
        acc[i][j] = __builtin_amdgcn_mfma_f32_16x16x32_bf16(a_hi[i], b_hi[j], acc[i][j], 0, 0, 0);
    #pragma unroll
    for (int i = 0; i < 4; i++)
      #pragma unroll
      for (int j = 0; j < 4; j++) {
        acc[i][j] = __builtin_amdgcn_mfma_f32_16x16x32_bf16(a_hi[i], b_lo[j], acc[i][j], 0, 0, 0);
        acc[i][j] = __builtin_amdgcn_mfma_f32_16x16x32_bf16(a_lo[i], b_hi[j], acc[i][j], 0, 0, 0);
      }
  }
#undef STAGE

  // ---- epilogue: D layout col=lane&15, row=fq*4+reg ----
  #pragma unroll
  for (int j = 0; j < 4; j++) {
    int col = cb + wn + j * 16 + fr;
    const float* bp = (col < DM) ? bias0 : bias1;
    float* Cp = (col < DM) ? C0 : C1;
    int cc = col & (DM - 1);
    float bv = bp[cc];
    #pragma unroll
    for (int i = 0; i < 4; i++) {
      int row0 = rb + wm + i * 16 + fq * 4;
      #pragma unroll
      for (int r = 0; r < 4; r++) {
        int row = row0 + r;
        long off = (long)row * DM + (long)(row >> 12) * rowJump + cc;
        float v = acc[i][j][r] + bv;
        if (resid) v += resid[off];
        Cp[off] = v;
      }
    }
  }
}

// M[b,h,l] for ALL 8 heads by one wave per (b,l): lane = h*8+j, 8 dims/lane.
// L2-locality: 27 samples visited in 8 passes over 512-row K chunks.
__global__ __launch_bounds__(256) void mscore_kernel(const float* __restrict__ Q, const float* __restrict__ K,
                                                     const int* __restrict__ idx, float* __restrict__ M)
{
  const int wl = threadIdx.x >> 6, lane = threadIdx.x & 63;
  const int bl = blockIdx.x * 4 + wl;       // b*4096 + l
  const int b = bl >> 12, l = bl & (SEQ - 1);

  const float4* qp = (const float4*)(Q + (long)bl * DM + lane * 8);
  float4 q0 = qp[0], q1 = qp[1];

  const int* ip = idx + l * UU;
  int idxv = ip[lane < UU ? lane : 0];
  int chv = idxv >> 9;                      // chunk id (512 rows/chunk)

  const float* kb = K + ((long)b << 12) * DM + lane * 8;
  float mx = -INFINITY, sm = 0.f;
  #pragma unroll 1
  for (int c = 0; c < 8; c++) {
    unsigned long long msk = __ballot(chv == c) & ((1ull << UU) - 1ull);
    while (msk) {
      int s = __builtin_ctzll(msk);
      msk &= msk - 1;
      int kl = __shfl(idxv, s, 64);
      const float4* kp = (const float4*)(kb + (long)kl * DM);
      float4 k0 = kp[0], k1 = kp[1];
      float dot;
      dot = q0.x * k0.x;
      dot = fmaf(q0.y, k0.y, dot); dot = fmaf(q0.z, k0.z, dot); dot = fmaf(q0.w, k0.w, dot);
      dot = fmaf(q1.x, k1.x, dot); dot = fmaf(q1.y, k1.y, dot);
      dot = fmaf(q1.z, k1.z, dot); dot = fmaf(q1.w, k1.w, dot);
      dot += __shfl_xor(dot, 1, 64);
      dot += __shfl_xor(dot, 2, 64);
      dot += __shfl_xor(dot, 4, 64);
      mx = fmaxf(mx, dot);
      sm += dot;
    }
  }
  if ((lane & 7) == 0) {
    int h = lane >> 3;
    M[(((long)b * NH + h) << 12) + l] = mx - sm * (1.0f / (float)SEQ);
  }
}

// Stable top-27 of 4096 per (b,h). Ties: lower index first (lax.top_k).
__global__ __launch_bounds__(256) void topk_kernel(const float* __restrict__ M, int* __restrict__ topidx)
{
  __shared__ float vals[SEQ];
  __shared__ float rv[256];
  __shared__ int   ri[256];
  const float* m = M + (long)blockIdx.x * SEQ;
  for (int i = threadIdx.x; i < SEQ; i += 256) vals[i] = m[i];
  __syncthreads();
  for (int it = 0; it < UU; it++) {
    float bv = -INFINITY; int bi = 0x7fffffff;
    for (int i = threadIdx.x; i < SEQ; i += 256) {
      float v = vals[i];
      if (v > bv) { bv = v; bi = i; }
    }
    rv[threadIdx.x] = bv; ri[threadIdx.x] = bi;
    __syncthreads();
    for (int s = 128; s > 0; s >>= 1) {
      if (threadIdx.x < s) {
        float ov = rv[threadIdx.x + s]; int oi = ri[threadIdx.x + s];
        if (ov > rv[threadIdx.x] || (ov == rv[threadIdx.x] && oi < ri[threadIdx.x])) {
          rv[threadIdx.x] = ov; ri[threadIdx.x] = oi;
        }
      }
      __syncthreads();
    }
    if (threadIdx.x == 0) { topidx[blockIdx.x * UU + it] = ri[0]; vals[ri[0]] = -INFINITY; }
    __syncthreads();
  }
}

__global__ __launch_bounds__(512) void vmean_partial(const float* __restrict__ V, float* __restrict__ vsum)
{
  int b = blockIdx.x >> 5, chunk = blockIdx.x & 31;
  int c = threadIdx.x;
  const float* p = V + ((long)b * SEQ + chunk * 128) * DM + c;
  float s = 0.f;
  for (int l = 0; l < 128; l++) s += p[(long)l * DM];
  atomicAdd(&vsum[b * DM + c], s);
}

// Flash-style chunked attention for the 27 selected queries.
__global__ __launch_bounds__(256) void attn_part(const float* __restrict__ Q, const float* __restrict__ K,
                                                 const float* __restrict__ V, const int* __restrict__ topidx,
                                                 float* __restrict__ partial)
{
  __shared__ float Qs[UU][HD];
  __shared__ float S[UU][CS];
  __shared__ float Vt[CS][HD];
  __shared__ float m_s[UU], l_s[UU];

  const int t = threadIdx.x;
  const int bh = blockIdx.x;
  const int chunk = blockIdx.y;
  const int b = bh >> 3, h = bh & 7;
  const long kbase = ((long)(b << 12) + chunk * CS) * DM + h * HD;
  const int* tp = topidx + bh * UU;

  for (int i = t; i < UU * HD; i += 256) {
    int u = i >> 6, d = i & 63;
    Qs[u][d] = Q[((long)(b << 12) + tp[u]) * DM + h * HD + d];
  }
  for (int i = t; i < CS * (HD / 4); i += 256) {
    int row = i >> 4, c4 = (i & 15) << 2;
    *(float4*)&Vt[row][c4] = *(const float4*)(V + kbase + (long)row * DM + c4);
  }
  __syncthreads();

  {
    const int l = t >> 1, half = t & 1, d0 = half * 32;
    const float* kp = K + kbase + (long)l * DM + d0;
    float4 kr[8];
    #pragma unroll
    for (int j = 0; j < 8; j++) kr[j] = *(const float4*)(kp + j * 4);
    #pragma unroll 1
    for (int u = 0; u < UU; u++) {
      const float4* qf = (const float4*)&Qs[u][d0];
      float dot = 0.f;
      #pragma unroll
      for (int j = 0; j < 8; j++) {
        float4 q = qf[j];
        dot = fmaf(q.x, kr[j].x, dot); dot = fmaf(q.y, kr[j].y, dot);
        dot = fmaf(q.z, kr[j].z, dot); dot = fmaf(q.w, kr[j].w, dot);
      }
      float tot = dot + __shfl_xor(dot, 1, 64);
      if (half == 0) S[u][l] = tot * 0.125f;
    }
  }
  __syncthreads();

  {
    const int u = t >> 3, il = t & 7;
    if (u < UU) {
      float mx = -INFINITY;
      for (int l = il; l < CS; l += 8) mx = fmaxf(mx, S[u][l]);
      #pragma unroll
      for (int m = 1; m < 8; m <<= 1) mx = fmaxf(mx, __shfl_xor(mx, m, 64));
      float ps = 0.f;
      for (int l = il; l < CS; l += 8) {
        float e = expf(S[u][l] - mx);
        S[u][l] = e;
        ps += e;
      }
      #pragma unroll
      for (int m = 1; m < 8; m <<= 1) ps += __shfl_xor(ps, m, 64);
      if (il == 0) { m_s[u] = mx; l_s[u] = ps; }
    }
  }
  __syncthreads();

  {
    const int d = t & 63, g = t >> 6;
    for (int u = g; u < UU; u += 4) {
      float acc = 0.f;
      #pragma unroll 4
      for (int l = 0; l < CS; l += 4) {
        float4 p4 = *(const float4*)&S[u][l];
        acc = fmaf(p4.x, Vt[l][d],     acc);
        acc = fmaf(p4.y, Vt[l + 1][d], acc);
        acc = fmaf(p4.z, Vt[l + 2][d], acc);
        acc = fmaf(p4.w, Vt[l + 3][d], acc);
      }
      float* pp = partial + (((long)bh * NC + chunk) * UU + u) * PSTRIDE;
      pp[2 + d] = acc;
      if (d == 0) { pp[0] = m_s[u]; pp[1] = l_s[u]; }
    }
  }
}

// Merge partials; write result directly into bf16 hi/lo planes (split).
__global__ __launch_bounds__(64) void attn_merge_bf(const float* __restrict__ partial, const int* __restrict__ topidx,
                                                    u16* __restrict__ hi, u16* __restrict__ lo)
{
  int g = blockIdx.x;
  int bh = g / UU, u = g % UU;
  int b = bh >> 3, h = bh & 7;
  int d = threadIdx.x;
  float M = -INFINITY, S = 0.f, acc = 0.f;
  for (int c = 0; c < NC; c++) {
    const float* pp = partial + (((long)bh * NC + c) * UU + u) * PSTRIDE;
    float mc = pp[0], sc = pp[1], a = pp[2 + d];
    if (mc > M) {
      float r = expf(M - mc);
      acc *= r; S *= r; M = mc;
    }
    float w = expf(mc - M);
    acc = fmaf(a, w, acc);
    S = fmaf(sc, w, S);
  }
  int ql = topidx[g];
  long o = ((long)(b << 12) + ql) * DM + h * HD + d;
  u16 hv, lv;
  f2bf_split(acc / S, hv, lv);
  hi[o] = hv; lo[o] = lv;
}

// Broadcast V-mean into the ctx bf16 hi/lo planes (split).
__global__ __launch_bounds__(256) void ctx_fill_bf(const float* __restrict__ vsum,
                                                   u16* __restrict__ hi, u16* __restrict__ lo)
{
  long g = (long)blockIdx.x * 256 + threadIdx.x;   // 4 elems per thread
  int b = (int)(g >> 19);
  int c4 = (int)(g & 127);
  float4 v = ((const float4*)vsum)[b * 128 + c4];
  const float s = 1.0f / (float)SEQ;
  float xv[4] = { v.x * s, v.y * s, v.z * s, v.w * s };
  union { short4v v; u16 s[4]; } h, l;
  #pragma unroll
  for (int e = 0; e < 4; e++) f2bf_split(xv[e], h.s[e], l.s[e]);
  ((short4v*)hi)[g] = h.v;
  ((short4v*)lo)[g]  = l.v;
}

__global__ __launch_bounds__(256) void add_upper(const float* __restrict__ xs, const float* __restrict__ xp2,
                                                 float* __restrict__ out)
{
  long g = (long)blockIdx.x * 256 + threadIdx.x;
  int b = (int)(g >> 19);
  long rem = g & 524287;
  float4 p = ((const float4*)xp2)[g];
  long o = ((long)b * 8192 + SEQ) * 128 + rem;
  float4 x = ((const float4*)xs)[o];
  x.x += p.x; x.y += p.y; x.z += p.z; x.w += p.w;
  ((float4*)out)[o] = x;
}

extern "C" void kernel_launch(void* const* d_in, const int* in_sizes, int n_in,
                              void* d_out, int out_size, void* d_ws, size_t ws_size,
                              hipStream_t stream)
{
  const float* xs  = (const float*)d_in[0];
  const float* xd  = (const float*)d_in[1];
  const float* xp  = (const float*)d_in[2];
  const float* w0q = (const float*)d_in[3];
  const float* w0k = (const float*)d_in[4];
  const float* w0v = (const float*)d_in[5];
  const float* w0o = (const float*)d_in[6];
  const float* b0q = (const float*)d_in[7];
  const float* b0k = (const float*)d_in[8];
  const float* b0v = (const float*)d_in[9];
  const float* b0o = (const float*)d_in[10];
  const float* w1q = (const float*)d_in[11];
  const float* w1k = (const float*)d_in[12];
  const float* w1v = (const float*)d_in[13];
  const float* w1o = (const float*)d_in[14];
  const float* b1q = (const float*)d_in[15];
  const float* b1k = (const float*)d_in[16];
  const float* b1v = (const float*)d_in[17];
  const float* b1o = (const float*)d_in[18];
  float* out = (float*)d_out;

  const long BIG = (long)NB * SEQ * DM;   // 8 Mi floats = 32 MB
  float* A  = (float*)d_ws;
  float* Bb = A  + BIG;
  float* Cc = Bb + BIG;
  float* Dd = Cc + BIG;
  float* ex = Dd + BIG;
  float* Pq  = ex + BIG;     // plane pair 1: hi | lo (bf16)
  float* Pkv = Pq + BIG;     // plane pair 2

  int*   idxbuf = (int*)ex;
  float* Mbuf   = ex + NIDX;
  int*   topidx = (int*)(Mbuf + (long)NB * NH * SEQ);
  float* vsum   = (float*)(topidx + NB * NH * UU);
  u16*   wpl    = (u16*)(ex + (1 << 20));   // +4 MB: 8 hi planes then 8 lo planes, 8 MB

  u16* Pq_hi  = (u16*)Pq;   u16* Pq_lo  = Pq_hi  + BIG;
  u16* Pkv_hi = (u16*)Pkv;  u16* Pkv_lo = Pkv_hi + BIG;
  auto whi = [&](int i){ return wpl + (long)i * 262144; };
  auto wlo = [&](int i){ return wpl + 8L * 262144 + (long)i * 262144; };

  dim3 gg(128, 4);     // plain 512-col GEMM
  dim3 gkv(128, 8);    // fused K|V GEMM (1024 cols)
  dim3 ag(NB * NH, NC);
  u32 k2a, k2b;

  // ---------- one-time: W^T hi/lo planes for all 8 weights ----------
  WPtrs wp;
  wp.w[0] = w0q; wp.w[1] = w0k; wp.w[2] = w0v; wp.w[3] = w0o;
  wp.w[4] = w1q; wp.w[5] = w1k; wp.w[6] = w1v; wp.w[7] = w1o;
  convw_kernel<<<dim3(512, 8), 256, 0, stream>>>(wp, wpl);

  // ---------- layer 0: xp2 = attn_layer(q=xp; kv=xd), key 42 ----------
  threefry2x32(0u, 42u, 0u, 1u, &k2a, &k2b);
  gen_idx_kernel<<<(NIDX + 255) / 256, 256, 0, stream>>>(k2a, k2b, idxbuf);
  conv_split<<<4096, 256, 0, stream>>>(xp, Pq_hi, Pq_lo);
  conv_split<<<4096, 256, 0, stream>>>(xd, Pkv_hi, Pkv_lo);
  gemm_bf<<<gg, 256, 0, stream>>>(Pq_hi,  Pq_lo,  whi(0), wlo(0), b0q, b0q, A,  A,  nullptr, 0);
  gemm_bf<<<gkv, 256, 0, stream>>>(Pkv_hi, Pkv_lo, whi(1), wlo(1), b0k, b0v, Bb, Cc, nullptr, 0);  // K->Bb, V->Cc
  mscore_kernel<<<NB * SEQ / 4, 256, 0, stream>>>(A, Bb, idxbuf, Mbuf);
  topk_kernel<<<NB * NH, 256, 0, stream>>>(Mbuf, topidx);
  hipMemsetAsync(vsum, 0, NB * DM * sizeof(float), stream);
  vmean_partial<<<NB * 32, 512, 0, stream>>>(Cc, vsum);
  attn_part<<<ag, 256, 0, stream>>>(A, Bb, Cc, topidx, Dd);
  ctx_fill_bf<<<8192, 256, 0, stream>>>(vsum, Pq_hi, Pq_lo);          // ctx planes (Pq consumed by Q-gemm)
  attn_merge_bf<<<NB * NH * UU, 64, 0, stream>>>(Dd, topidx, Pq_hi, Pq_lo);
  gemm_bf<<<gg, 256, 0, stream>>>(Pq_hi, Pq_lo, whi(3), wlo(3), b0o, b0o, Bb, Bb, nullptr, 0);     // xp2 fp32
  add_upper<<<8192, 256, 0, stream>>>(xs, Bb, out);

  // ---------- layer 1: xd2 = attn_layer(q=xd; kv=xp2), key 43 ----------
  threefry2x32(0u, 43u, 0u, 1u, &k2a, &k2b);
  gen_idx_kernel<<<(NIDX + 255) / 256, 256, 0, stream>>>(k2a, k2b, idxbuf);
  gemm_bf<<<gg, 256, 0, stream>>>(Pkv_hi, Pkv_lo, whi(4), wlo(4), b1q, b1q, A, A, nullptr, 0);     // xd planes reused
  conv_split<<<4096, 256, 0, stream>>>(Bb, Pq_hi, Pq_lo);                                          // xp2 planes
  gemm_bf<<<gkv, 256, 0, stream>>>(Pq_hi, Pq_lo, whi(5), wlo(5), b1k, b1v, Cc, Dd, nullptr, 0);    // K->Cc, V->Dd
  mscore_kernel<<<NB * SEQ / 4, 256, 0, stream>>>(A, Cc, idxbuf, Mbuf);
  topk_kernel<<<NB * NH, 256, 0, stream>>>(Mbuf, topidx);
  hipMemsetAsync(vsum, 0, NB * DM * sizeof(float), stream);
  vmean_partial<<<NB * 32, 512, 0, stream>>>(Dd, vsum);
  attn_part<<<ag, 256, 0, stream>>>(A, Cc, Dd, topidx, Bb);
  ctx_fill_bf<<<8192, 256, 0, stream>>>(vsum, Pkv_hi, Pkv_lo);        // ctx planes (Pkv free after Q-gemm)
  attn_merge_bf<<<NB * NH * UU, 64, 0, stream>>>(Bb, topidx, Pkv_hi, Pkv_lo);
  gemm_bf<<<gg, 256, 0, stream>>>(Pkv_hi, Pkv_lo, whi(7), wlo(7), b1o, b1o, out, out, xs, SEQ * DM);
}